// Round 5
// baseline (7344.486 us; speedup 1.0000x reference)
//
#include <hip/hip_runtime.h>
#include <hip/hip_bf16.h>

// NCA2D: B=16, H=128, W=128, C=16, T=8, HID=128, N_STEPS=64, FC0_IN=49
constexpr int B = 16, H = 128, W = 128, C = 16, T = 8, HID = 128, NSTEPS = 64;
constexpr int FC0_IN = 49;
constexpr int K0 = 64;   // fc0 K padded to 64

using f32x4  = __attribute__((ext_vector_type(4))) float;
using bf16x8 = __attribute__((ext_vector_type(8))) short;

__device__ __forceinline__ unsigned short bf16_hi(float v) {
    __hip_bfloat16 h = __float2bfloat16(v);
    return *reinterpret_cast<unsigned short*>(&h);
}
__device__ __forceinline__ float bf16_f32(unsigned short u) {
    unsigned int x = ((unsigned int)u) << 16;
    union { unsigned int u; float f; } c; c.u = x; return c.f;
}

// Split fc0_w -> [HID][64] bf16 hi/lo (K zero-padded 49->64), fc1_w -> [C][HID] hi/lo.
__global__ void prep_weights(const float* __restrict__ fc0_w, const float* __restrict__ fc1_w,
                             unsigned short* __restrict__ w0hi, unsigned short* __restrict__ w0lo,
                             unsigned short* __restrict__ w1hi, unsigned short* __restrict__ w1lo) {
    const int tid = threadIdx.x;
    for (int idx = tid; idx < HID * K0; idx += 256) {
        const int n = idx >> 6, k = idx & 63;
        const float v = (k < FC0_IN) ? fc0_w[n * FC0_IN + k] : 0.0f;
        const unsigned short hi = bf16_hi(v);
        w0hi[idx] = hi;
        w0lo[idx] = bf16_hi(v - bf16_f32(hi));
    }
    for (int idx = tid; idx < C * HID; idx += 256) {
        const float v = fc1_w[idx];
        const unsigned short hi = bf16_hi(v);
        w1hi[idx] = hi;
        w1lo[idx] = bf16_hi(v - bf16_f32(hi));
    }
}

// Per block: 256 threads = 4 waves; each wave owns 16 consecutive cells of one image row.
// fc0: D[16 cells x 128 hid] via 8 n-tiles x 2 k-steps x 3 split-products.
// fc1: transpose h through LDS, D2[16 cells x 16 ch] via 4 k-steps x 3 products.
__global__ __launch_bounds__(256, 4) void nca_step(
    const float* __restrict__ x_in, float* __restrict__ x_out,
    const float* __restrict__ p0_w, const float* __restrict__ p0_b,
    const float* __restrict__ p1_w, const float* __restrict__ p1_b,
    const unsigned short* __restrict__ w0hi, const unsigned short* __restrict__ w0lo,
    const float* __restrict__ fc0_b,
    const unsigned short* __restrict__ w1hi, const unsigned short* __restrict__ w1lo,
    const int* __restrict__ acq, float* __restrict__ out, int step)
{
    __shared__ float hlds[4][16][132];   // per-wave h tile, stride 132 to spread banks

    const int tid  = threadIdx.x;
    const int wv   = tid >> 6;
    const int lane = tid & 63;
    const int m    = lane & 15;          // A-row / D-col index
    const int g    = lane >> 4;          // k-group
    const int cellbase = blockIdx.x * 64 + wv * 16;
    const int b     = cellbase >> 14;
    const int hrow  = (cellbase >> 7) & (H - 1);
    const int wbase = cellbase & (W - 1);
    const int wcol  = wbase + m;         // this lane's conv cell column

    // ---- depthwise conv: each lane computes 8 channels of ONE conv for cell (cellbase+m)
    // g0: z2 ch0-7 | g1: z2 ch8-15 | g2: z1 ch0-7 | g3: z1 ch8-15
    const float* pw = (g >= 2) ? p0_w : p1_w;
    const float* pb = (g >= 2) ? p0_b : p1_b;
    const int ch = (g & 1) * 8;
    float z[8], xcen[8];
    #pragma unroll
    for (int j = 0; j < 8; ++j) z[j] = pb[ch + j];
    #pragma unroll
    for (int di = -1; di <= 1; ++di) {
        int hh = hrow + di; hh = (hh < 0) ? 1 : ((hh > H - 1) ? H - 2 : hh);
        #pragma unroll
        for (int dj = -1; dj <= 1; ++dj) {
            int ww = wcol + dj; ww = (ww < 0) ? 1 : ((ww > W - 1) ? W - 2 : ww);
            const float4* p4 = reinterpret_cast<const float4*>(
                x_in + (((size_t)(b * H + hh) * W + ww) << 4) + ch);
            const float4 q0 = p4[0], q1 = p4[1];
            const float xv[8] = {q0.x, q0.y, q0.z, q0.w, q1.x, q1.y, q1.z, q1.w};
            const int tap = (di + 1) * 3 + (dj + 1);
            #pragma unroll
            for (int j = 0; j < 8; ++j)
                z[j] = fmaf(xv[j], pw[tap * 16 + ch + j], z[j]);
            if (di == 0 && dj == 0) {
                #pragma unroll
                for (int j = 0; j < 8; ++j) xcen[j] = xv[j];
            }
        }
    }

    // ---- assemble y fragments (K=64: k0-31 = [x | z1], k32-63 = [z2 | prog | pad])
    const float prog = (float)step * (1.0f / (float)NSTEPS);
    float fy0[8], fy1[8];
    #pragma unroll
    for (int j = 0; j < 8; ++j) {
        fy0[j] = (g < 2) ? xcen[j] : z[j];
        fy1[j] = (g < 2) ? z[j] : ((g == 2 && j == 0) ? prog : 0.0f);
    }
    bf16x8 a0h, a0l, a1h, a1l;
    #pragma unroll
    for (int j = 0; j < 8; ++j) {
        const unsigned short h0 = bf16_hi(fy0[j]);
        a0h[j] = (short)h0;
        a0l[j] = (short)bf16_hi(fy0[j] - bf16_f32(h0));
        const unsigned short h1 = bf16_hi(fy1[j]);
        a1h[j] = (short)h1;
        a1l[j] = (short)bf16_hi(fy1[j] - bf16_f32(h1));
    }

    // ---- fc0: 8 n-tiles of 16 hid each
    const int kb = g * 8;
    #pragma unroll 2
    for (int nt = 0; nt < 8; ++nt) {
        const int n = nt * 16 + m;
        const bf16x8 b0h = *reinterpret_cast<const bf16x8*>(w0hi + n * K0 + kb);
        const bf16x8 b0l = *reinterpret_cast<const bf16x8*>(w0lo + n * K0 + kb);
        const bf16x8 b1h = *reinterpret_cast<const bf16x8*>(w0hi + n * K0 + 32 + kb);
        const bf16x8 b1l = *reinterpret_cast<const bf16x8*>(w0lo + n * K0 + 32 + kb);
        f32x4 acc = {0.0f, 0.0f, 0.0f, 0.0f};
        acc = __builtin_amdgcn_mfma_f32_16x16x32_bf16(a0h, b0h, acc, 0, 0, 0);
        acc = __builtin_amdgcn_mfma_f32_16x16x32_bf16(a0l, b0h, acc, 0, 0, 0);
        acc = __builtin_amdgcn_mfma_f32_16x16x32_bf16(a0h, b0l, acc, 0, 0, 0);
        acc = __builtin_amdgcn_mfma_f32_16x16x32_bf16(a1h, b1h, acc, 0, 0, 0);
        acc = __builtin_amdgcn_mfma_f32_16x16x32_bf16(a1l, b1h, acc, 0, 0, 0);
        acc = __builtin_amdgcn_mfma_f32_16x16x32_bf16(a1h, b1l, acc, 0, 0, 0);
        const float bias = fc0_b[n];
        #pragma unroll
        for (int r = 0; r < 4; ++r)
            hlds[wv][g * 4 + r][n] = fmaxf(acc[r] + bias, 0.0f);  // D: row=g*4+r, col=n
    }
    __syncthreads();

    // ---- fc1: h[16 x 128] x W1^T[128 x 16]
    f32x4 acc2 = {0.0f, 0.0f, 0.0f, 0.0f};
    #pragma unroll
    for (int kk = 0; kk < 4; ++kk) {
        const float* hp = &hlds[wv][m][kk * 32 + kb];
        const float4 hq0 = *reinterpret_cast<const float4*>(hp);
        const float4 hq1 = *reinterpret_cast<const float4*>(hp + 4);
        const float hv[8] = {hq0.x, hq0.y, hq0.z, hq0.w, hq1.x, hq1.y, hq1.z, hq1.w};
        bf16x8 ah, al;
        #pragma unroll
        for (int j = 0; j < 8; ++j) {
            const unsigned short hh2 = bf16_hi(hv[j]);
            ah[j] = (short)hh2;
            al[j] = (short)bf16_hi(hv[j] - bf16_f32(hh2));
        }
        const bf16x8 bh = *reinterpret_cast<const bf16x8*>(w1hi + m * HID + kk * 32 + kb);
        const bf16x8 bl = *reinterpret_cast<const bf16x8*>(w1lo + m * HID + kk * 32 + kb);
        acc2 = __builtin_amdgcn_mfma_f32_16x16x32_bf16(ah, bh, acc2, 0, 0, 0);
        acc2 = __builtin_amdgcn_mfma_f32_16x16x32_bf16(al, bh, acc2, 0, 0, 0);
        acc2 = __builtin_amdgcn_mfma_f32_16x16x32_bf16(ah, bl, acc2, 0, 0, 0);
    }

    // ---- epilogue: x_new = x_old + sigmoid(dx); D2: row=cell g*4+r, col=ch m
    #pragma unroll
    for (int r = 0; r < 4; ++r) {
        const int cellr = cellbase + g * 4 + r;
        const float xold = x_in[(size_t)cellr * C + m];
        const float s = 1.0f / (1.0f + __expf(-acc2[r]));
        const float xn = xold + s;
        x_out[(size_t)cellr * C + m] = xn;
        if (step > 0) {
            #pragma unroll
            for (int t = 0; t < T; ++t) {
                if (acq[b * T + t] == step) {
                    out[((((size_t)(b * T + t) * H + hrow) * W + (wbase + g * 4 + r)) << 4) + m] = xn;
                }
            }
        }
    }
}

extern "C" void kernel_launch(void* const* d_in, const int* in_sizes, int n_in,
                              void* d_out, int out_size, void* d_ws, size_t ws_size,
                              hipStream_t stream) {
    const float* inputs = (const float*)d_in[0];
    const int*   acq    = (const int*)d_in[1];
    const float* p0_w   = (const float*)d_in[2];
    const float* p0_b   = (const float*)d_in[3];
    const float* p1_w   = (const float*)d_in[4];
    const float* p1_b   = (const float*)d_in[5];
    const float* fc0_w  = (const float*)d_in[6];
    const float* fc0_b  = (const float*)d_in[7];
    const float* fc1_w  = (const float*)d_in[8];
    float* out = (float*)d_out;

    const size_t state_elems = (size_t)B * H * W * C;   // 16 MB each
    float* bufA = (float*)d_ws;
    float* bufB = bufA + state_elems;
    unsigned short* w0hi = (unsigned short*)(bufB + state_elems);
    unsigned short* w0lo = w0hi + HID * K0;
    unsigned short* w1hi = w0lo + HID * K0;
    unsigned short* w1lo = w1hi + C * HID;

    hipMemsetAsync(d_out, 0, (size_t)out_size * sizeof(float), stream);
    prep_weights<<<1, 256, 0, stream>>>(fc0_w, fc1_w, w0hi, w0lo, w1hi, w1lo);

    const int n_cells = B * H * W;                // 262144
    const dim3 grid(n_cells / 64), block(256);    // 4096 blocks, 4 waves each

    const float* xin = inputs;
    for (int step = 0; step < NSTEPS; ++step) {
        float* xout = (step & 1) ? bufB : bufA;
        nca_step<<<grid, block, 0, stream>>>(
            xin, xout, p0_w, p0_b, p1_w, p1_b,
            w0hi, w0lo, fc0_b, w1hi, w1lo, acq, out, step);
        xin = xout;
    }
}

// Round 6
// 2960.403 us; speedup vs baseline: 2.4809x; 2.4809x over previous
//
#include <hip/hip_runtime.h>
#include <hip/hip_bf16.h>

// NCA2D: B=16, H=128, W=128, C=16, T=8, HID=128, N_STEPS=64, FC0_IN=49
constexpr int B = 16, H = 128, W = 128, C = 16, T = 8, HID = 128, NSTEPS = 64;

using f32x4  = __attribute__((ext_vector_type(4))) float;
using bf16x8 = __attribute__((ext_vector_type(8))) short;

__device__ __forceinline__ unsigned short bf16_hi(float v) {
    __hip_bfloat16 h = __float2bfloat16(v);
    return *reinterpret_cast<unsigned short*>(&h);
}
__device__ __forceinline__ float bf16_f32(unsigned short u) {
    union { unsigned int u; float f; } c; c.u = ((unsigned int)u) << 16; return c.f;
}

// Packed fragment table (40 rows x 64 lanes x 16B = 40KB):
//  rows 0..31 : fc0 B-frags, row = nt*4 + f, f in {b0h,b0l,b1h,b1l}
//               entry(row, l=(g,m))[j] = split(fc0_w[nt*16+m][ (f>=2?32:0)+g*8+j ]) (0-pad k>=49)
//  rows 32..39: fc1 A-frags (W1), row = 32 + ks*2 + f, f in {hi,lo}
//               entry[j] = split(fc1_w[m][ks*32+g*8+j])
__global__ void prep_pack(const float* __restrict__ fc0_w, const float* __restrict__ fc1_w,
                          unsigned short* __restrict__ pack) {
    for (int e = threadIdx.x; e < 40 * 64; e += 256) {
        const int row = e >> 6, l = e & 63;
        const int m = l & 15, g = l >> 4;
        unsigned short v[8];
        if (row < 32) {
            const int nt = row >> 2, f = row & 3;
            const int n = nt * 16 + m;
            const int kbase = ((f >= 2) ? 32 : 0) + g * 8;
            #pragma unroll
            for (int j = 0; j < 8; ++j) {
                const int k = kbase + j;
                const float x = (k < 49) ? fc0_w[n * 49 + k] : 0.0f;
                const unsigned short hi = bf16_hi(x);
                v[j] = (f & 1) ? bf16_hi(x - bf16_f32(hi)) : hi;
            }
        } else {
            const int rr = row - 32, ks = rr >> 1, f = rr & 1;
            #pragma unroll
            for (int j = 0; j < 8; ++j) {
                const float x = fc1_w[m * HID + ks * 32 + g * 8 + j];
                const unsigned short hi = bf16_hi(x);
                v[j] = f ? bf16_hi(x - bf16_f32(hi)) : hi;
            }
        }
        #pragma unroll
        for (int j = 0; j < 8; ++j) pack[e * 8 + j] = v[j];
    }
}

// 4 waves/block, 16 cells/wave (one row segment). LDS: 32KB staged fc0 frags + 32KB h tiles = 64KB
// -> 2 blocks/CU. fc1 computed swapped (D2 = W1 . h^T) so the epilogue is register-local with
// fully coalesced dwordx4 loads/stores.
__global__ __launch_bounds__(256, 2) void nca_step(
    const float* __restrict__ x_in, float* __restrict__ x_out,
    const float* __restrict__ p0_w, const float* __restrict__ p0_b,
    const float* __restrict__ p1_w, const float* __restrict__ p1_b,
    const unsigned short* __restrict__ pack, const float* __restrict__ fc0_b,
    const int* __restrict__ acq, float* __restrict__ out, int step)
{
    __shared__ float wlds[32 * 256];   // fc0 B-frag rows, identity layout (bank-uniform reads)
    __shared__ float hlds[4 * 2048];   // per-wave h[16 cells][128 hid], 16B-granular XOR swizzle

    const int tid  = threadIdx.x;
    const int wv   = tid >> 6;
    const int lane = tid & 63;
    const int m    = lane & 15;
    const int g    = lane >> 4;

    // ---- stage fc0 frag table global->LDS (8 x dwordx4 per thread, coalesced)
    #pragma unroll
    for (int e0 = 0; e0 < 2048; e0 += 256) {
        const int e = e0 + tid;
        const int4 v = *reinterpret_cast<const int4*>(pack + (size_t)e * 8);
        *reinterpret_cast<int4*>(&wlds[e * 4]) = v;
    }

    const int cellbase = blockIdx.x * 64 + wv * 16;
    const int b     = cellbase >> 14;
    const int hrow  = (cellbase >> 7) & (H - 1);
    const int wbase = cellbase & (W - 1);
    const int wcol  = wbase + m;

    // ---- depthwise conv (f32 VALU): lane (g,m) -> 8 ch of one conv at cell cellbase+m
    // g0: z2 ch0-7 | g1: z2 ch8-15 | g2: z1 ch0-7 | g3: z1 ch8-15
    const float* pw = (g >= 2) ? p0_w : p1_w;
    const float* pb = (g >= 2) ? p0_b : p1_b;
    const int ch = (g & 1) * 8;
    float z[8], xcen[8];
    #pragma unroll
    for (int j = 0; j < 8; ++j) z[j] = pb[ch + j];
    #pragma unroll
    for (int di = -1; di <= 1; ++di) {
        int hh = hrow + di; hh = (hh < 0) ? 1 : ((hh > H - 1) ? H - 2 : hh);
        #pragma unroll
        for (int dj = -1; dj <= 1; ++dj) {
            int ww = wcol + dj; ww = (ww < 0) ? 1 : ((ww > W - 1) ? W - 2 : ww);
            const float4* p4 = reinterpret_cast<const float4*>(
                x_in + (((size_t)(b * H + hh) * W + ww) << 4) + ch);
            const float4 q0 = p4[0], q1 = p4[1];
            const float xv[8] = {q0.x, q0.y, q0.z, q0.w, q1.x, q1.y, q1.z, q1.w};
            const int tap = (di + 1) * 3 + (dj + 1);
            #pragma unroll
            for (int j = 0; j < 8; ++j)
                z[j] = fmaf(xv[j], pw[tap * 16 + ch + j], z[j]);
            if (di == 0 && dj == 0) {
                #pragma unroll
                for (int j = 0; j < 8; ++j) xcen[j] = xv[j];
            }
        }
    }

    // ---- early loads (latency hidden under fc0/fc1)
    const float4 xold4 = *reinterpret_cast<const float4*>(
        x_in + ((size_t)(cellbase + m) << 4) + g * 4);
    int snapmask = 0;
    if (step > 0) {
        #pragma unroll
        for (int t = 0; t < T; ++t)
            snapmask |= (acq[b * T + t] == step) ? (1 << t) : 0;
    }
    bf16x8 w1f[8];   // fc1 A-frags (W1 hi/lo), rows 32..39
    #pragma unroll
    for (int q = 0; q < 8; ++q)
        w1f[q] = *reinterpret_cast<const bf16x8*>(pack + ((32 + q) * 64 + lane) * 8);
    float bias[8];
    #pragma unroll
    for (int nt = 0; nt < 8; ++nt) bias[nt] = fc0_b[nt * 16 + m];

    // ---- assemble A-frags (K=64: k0-31 = [x | z1], k32-63 = [z2 | prog | pad])
    const float prog = (float)step * (1.0f / (float)NSTEPS);
    bf16x8 a0h, a0l, a1h, a1l;
    #pragma unroll
    for (int j = 0; j < 8; ++j) {
        const float f0 = (g < 2) ? xcen[j] : z[j];
        const float f1 = (g < 2) ? z[j] : ((g == 2 && j == 0) ? prog : 0.0f);
        const unsigned short h0 = bf16_hi(f0);
        a0h[j] = (short)h0;  a0l[j] = (short)bf16_hi(f0 - bf16_f32(h0));
        const unsigned short h1 = bf16_hi(f1);
        a1h[j] = (short)h1;  a1l[j] = (short)bf16_hi(f1 - bf16_f32(h1));
    }

    __syncthreads();   // staged wlds visible

    // ---- fc0: h[16 cells][128 hid]; D: lane(g,m) reg r -> h[cell g*4+r][hid nt*16+m]
    float* hb = hlds + (wv << 11);
    const int lb = lane << 2;   // this lane's 16B slot within a 1KB frag row
    #pragma unroll
    for (int nt = 0; nt < 8; ++nt) {
        const int rb = nt << 10;
        const bf16x8 b0h = *reinterpret_cast<const bf16x8*>(&wlds[rb + lb]);
        const bf16x8 b0l = *reinterpret_cast<const bf16x8*>(&wlds[rb + 256 + lb]);
        const bf16x8 b1h = *reinterpret_cast<const bf16x8*>(&wlds[rb + 512 + lb]);
        const bf16x8 b1l = *reinterpret_cast<const bf16x8*>(&wlds[rb + 768 + lb]);
        f32x4 acc = {0.0f, 0.0f, 0.0f, 0.0f};
        acc = __builtin_amdgcn_mfma_f32_16x16x32_bf16(a0h, b0h, acc, 0, 0, 0);
        acc = __builtin_amdgcn_mfma_f32_16x16x32_bf16(a0l, b0h, acc, 0, 0, 0);
        acc = __builtin_amdgcn_mfma_f32_16x16x32_bf16(a0h, b0l, acc, 0, 0, 0);
        acc = __builtin_amdgcn_mfma_f32_16x16x32_bf16(a1h, b1h, acc, 0, 0, 0);
        acc = __builtin_amdgcn_mfma_f32_16x16x32_bf16(a1l, b1h, acc, 0, 0, 0);
        acc = __builtin_amdgcn_mfma_f32_16x16x32_bf16(a1h, b1l, acc, 0, 0, 0);
        const int hid4 = (nt << 2) + (m >> 2), ml = m & 3;
        #pragma unroll
        for (int r = 0; r < 4; ++r) {
            const int cr = g * 4 + r;
            // swizzled store: f32 idx = cell*128 + ((hid4 ^ (cell&7))<<2) + (hid&3)
            hb[cr * 128 + (((hid4 ^ (cr & 7)) << 2) | ml)] = fmaxf(acc[r] + bias[nt], 0.0f);
        }
    }
    __syncthreads();

    // ---- fc1 swapped: D2 = W1 . h^T; lane(g,m) reads h[cell m][hid ks*32+g*8 .. +7]
    f32x4 acc2 = {0.0f, 0.0f, 0.0f, 0.0f};
    const int m7 = m & 7;
    #pragma unroll
    for (int ks = 0; ks < 4; ++ks) {
        const float4 h0 = *reinterpret_cast<const float4*>(
            &hb[m * 128 + ((((ks << 3) + (g << 1) + 0) ^ m7) << 2)]);
        const float4 h1 = *reinterpret_cast<const float4*>(
            &hb[m * 128 + ((((ks << 3) + (g << 1) + 1) ^ m7) << 2)]);
        const float hv[8] = {h0.x, h0.y, h0.z, h0.w, h1.x, h1.y, h1.z, h1.w};
        bf16x8 bh, bl;
        #pragma unroll
        for (int j = 0; j < 8; ++j) {
            const unsigned short hi = bf16_hi(hv[j]);
            bh[j] = (short)hi;
            bl[j] = (short)bf16_hi(hv[j] - bf16_f32(hi));
        }
        acc2 = __builtin_amdgcn_mfma_f32_16x16x32_bf16(w1f[ks * 2 + 0], bh, acc2, 0, 0, 0);
        acc2 = __builtin_amdgcn_mfma_f32_16x16x32_bf16(w1f[ks * 2 + 1], bh, acc2, 0, 0, 0);
        acc2 = __builtin_amdgcn_mfma_f32_16x16x32_bf16(w1f[ks * 2 + 0], bl, acc2, 0, 0, 0);
    }

    // ---- epilogue: D2 lane(g,m) reg r -> dx[ch g*4+r][cell cellbase+m]; coalesced 16B ops
    const size_t cell = (size_t)(cellbase + m);
    float4 xn;
    xn.x = xold4.x + 1.0f / (1.0f + __expf(-acc2[0]));
    xn.y = xold4.y + 1.0f / (1.0f + __expf(-acc2[1]));
    xn.z = xold4.z + 1.0f / (1.0f + __expf(-acc2[2]));
    xn.w = xold4.w + 1.0f / (1.0f + __expf(-acc2[3]));
    *reinterpret_cast<float4*>(x_out + (cell << 4) + g * 4) = xn;
    if (snapmask) {
        #pragma unroll
        for (int t = 0; t < T; ++t) {
            if (snapmask & (1 << t)) {
                *reinterpret_cast<float4*>(out + (size_t)(b * T + t) * (H * W * C)
                    + (((size_t)hrow * W + wbase + m) << 4) + g * 4) = xn;
            }
        }
    }
}

extern "C" void kernel_launch(void* const* d_in, const int* in_sizes, int n_in,
                              void* d_out, int out_size, void* d_ws, size_t ws_size,
                              hipStream_t stream) {
    const float* inputs = (const float*)d_in[0];
    const int*   acq    = (const int*)d_in[1];
    const float* p0_w   = (const float*)d_in[2];
    const float* p0_b   = (const float*)d_in[3];
    const float* p1_w   = (const float*)d_in[4];
    const float* p1_b   = (const float*)d_in[5];
    const float* fc0_w  = (const float*)d_in[6];
    const float* fc0_b  = (const float*)d_in[7];
    const float* fc1_w  = (const float*)d_in[8];
    float* out = (float*)d_out;

    const size_t state_elems = (size_t)B * H * W * C;   // 16 MB each
    float* bufA = (float*)d_ws;
    float* bufB = bufA + state_elems;
    unsigned short* pack = (unsigned short*)(bufB + state_elems);  // 40 KB

    hipMemsetAsync(d_out, 0, (size_t)out_size * sizeof(float), stream);
    prep_pack<<<1, 256, 0, stream>>>(fc0_w, fc1_w, pack);

    const int n_cells = B * H * W;                // 262144
    const dim3 grid(n_cells / 64), block(256);    // 4096 blocks, 4 waves each

    const float* xin = inputs;
    for (int step = 0; step < NSTEPS; ++step) {
        float* xout = (step & 1) ? bufB : bufA;
        nca_step<<<grid, block, 0, stream>>>(
            xin, xout, p0_w, p0_b, p1_w, p1_b,
            pack, fc0_b, acq, out, step);
        xin = xout;
    }
}

// Round 7
// 2104.470 us; speedup vs baseline: 3.4899x; 1.4067x over previous
//
#include <hip/hip_runtime.h>
#include <hip/hip_bf16.h>

// NCA2D: B=16, H=128, W=128, C=16, T=8, HID=128, N_STEPS=64, FC0_IN=49
constexpr int B = 16, H = 128, W = 128, C = 16, T = 8, HID = 128, NSTEPS = 64;

using f32x4  = __attribute__((ext_vector_type(4))) float;
using bf16x8 = __attribute__((ext_vector_type(8))) short;

__device__ __forceinline__ unsigned short bf16_hi(float v) {
    __hip_bfloat16 h = __float2bfloat16(v);
    return *reinterpret_cast<unsigned short*>(&h);
}
__device__ __forceinline__ float bf16_f32(unsigned short u) {
    union { unsigned int u; float f; } c; c.u = ((unsigned int)u) << 16; return c.f;
}

// Packed fragment table (40 rows x 64 lanes x 16B = 40KB):
//  rows 0..31 : fc0 B-frags, row = nt*4 + f, f in {b0h,b0l,b1h,b1l}
//  rows 32..39: fc1 A-frags (W1), row = 32 + ks*2 + f, f in {hi,lo}
__global__ void prep_pack(const float* __restrict__ fc0_w, const float* __restrict__ fc1_w,
                          unsigned short* __restrict__ pack) {
    for (int e = threadIdx.x; e < 40 * 64; e += 256) {
        const int row = e >> 6, l = e & 63;
        const int m = l & 15, g = l >> 4;
        unsigned short v[8];
        if (row < 32) {
            const int nt = row >> 2, f = row & 3;
            const int n = nt * 16 + m;
            const int kbase = ((f >= 2) ? 32 : 0) + g * 8;
            #pragma unroll
            for (int j = 0; j < 8; ++j) {
                const int k = kbase + j;
                const float x = (k < 49) ? fc0_w[n * 49 + k] : 0.0f;
                const unsigned short hi = bf16_hi(x);
                v[j] = (f & 1) ? bf16_hi(x - bf16_f32(hi)) : hi;
            }
        } else {
            const int rr = row - 32, ks = rr >> 1, f = rr & 1;
            #pragma unroll
            for (int j = 0; j < 8; ++j) {
                const float x = fc1_w[m * HID + ks * 32 + g * 8 + j];
                const unsigned short hi = bf16_hi(x);
                v[j] = f ? bf16_hi(x - bf16_f32(hi)) : hi;
            }
        }
        #pragma unroll
        for (int j = 0; j < 8; ++j) pack[e * 8 + j] = v[j];
    }
}

// Zero only the output slots whose acquire step is 0 (never written by snapshots).
// All other slots are fully rewritten every call at their acquire step.
__global__ void zero_acq0(const int* __restrict__ acq, float* __restrict__ out) {
    const int bt = blockIdx.x;                 // 0..B*T-1
    if (acq[bt] != 0) return;
    float4* p = reinterpret_cast<float4*>(out + (size_t)bt * (H * W * C));
    for (int i = threadIdx.x; i < (H * W * C) / 4; i += 256)
        p[i] = make_float4(0.0f, 0.0f, 0.0f, 0.0f);
}

// 4 waves/block, 4 tiles/block (256 consecutive cells = 2 image rows).
// LDS: 32KB staged fc0 frags + 32KB per-wave h tiles = 64KB -> 2 blocks/CU.
// Per tile: conv (f32 VALU) -> fc0 (MFMA, wlds->hlds) -> fc1 swapped (D2 = W1 . h^T)
// -> coalesced epilogue. Only ONE block barrier (after wlds staging); hlds is
// wave-private so within-wave DS ordering covers the fc0/fc1 hazards.
__global__ __launch_bounds__(256, 2) void nca_step(
    const float* __restrict__ x_in, float* __restrict__ x_out,
    const float* __restrict__ p0_w, const float* __restrict__ p0_b,
    const float* __restrict__ p1_w, const float* __restrict__ p1_b,
    const unsigned short* __restrict__ pack, const float* __restrict__ fc0_b,
    const int* __restrict__ acq, float* __restrict__ out, int step)
{
    __shared__ float wlds[32 * 256];   // fc0 B-frag rows, identity layout
    __shared__ float hlds[4 * 2048];   // per-wave h[16 cells][128 hid], 16B-XOR swizzle

    const int tid  = threadIdx.x;
    const int wv   = tid >> 6;
    const int lane = tid & 63;
    const int m    = lane & 15;
    const int g    = lane >> 4;

    // ---- stage fc0 frag table global->LDS (8 x dwordx4 per thread, coalesced)
    #pragma unroll
    for (int e0 = 0; e0 < 2048; e0 += 256) {
        const int e = e0 + tid;
        const int4 v = *reinterpret_cast<const int4*>(pack + (size_t)e * 8);
        *reinterpret_cast<int4*>(&wlds[e * 4]) = v;
    }

    const int blockbase = blockIdx.x * 256;
    const int b = blockbase >> 14;     // image index, uniform per block

    // ---- block-invariant loads (hidden under tile-0 conv)
    int snapmask = 0;
    if (step > 0) {
        #pragma unroll
        for (int t = 0; t < T; ++t)
            snapmask |= (acq[b * T + t] == step) ? (1 << t) : 0;
    }
    bf16x8 w1f[8];   // fc1 A-frags (W1 hi/lo)
    #pragma unroll
    for (int q = 0; q < 8; ++q)
        w1f[q] = *reinterpret_cast<const bf16x8*>(pack + ((32 + q) * 64 + lane) * 8);
    float bias[8];
    #pragma unroll
    for (int nt = 0; nt < 8; ++nt) bias[nt] = fc0_b[nt * 16 + m];

    const float prog = (float)step * (1.0f / (float)NSTEPS);
    const float* pw = (g >= 2) ? p0_w : p1_w;
    const float* pb = (g >= 2) ? p0_b : p1_b;
    const int ch = (g & 1) * 8;
    float* hb = hlds + (wv << 11);
    const int lb = lane << 2;
    const int m7 = m & 7;

    for (int t = 0; t < 4; ++t) {
        const int cellbase = blockbase + t * 64 + wv * 16;
        const int hrow  = (cellbase >> 7) & (H - 1);
        const int wbase = cellbase & (W - 1);
        const int wcol  = wbase + m;

        // ---- depthwise conv: lane (g,m) -> 8 ch of one conv at cell cellbase+m
        // g0: z2 ch0-7 | g1: z2 ch8-15 | g2: z1 ch0-7 | g3: z1 ch8-15
        float z[8], xcen[8];
        #pragma unroll
        for (int j = 0; j < 8; ++j) z[j] = pb[ch + j];
        #pragma unroll
        for (int di = -1; di <= 1; ++di) {
            int hh = hrow + di; hh = (hh < 0) ? 1 : ((hh > H - 1) ? H - 2 : hh);
            #pragma unroll
            for (int dj = -1; dj <= 1; ++dj) {
                int ww = wcol + dj; ww = (ww < 0) ? 1 : ((ww > W - 1) ? W - 2 : ww);
                const float4* p4 = reinterpret_cast<const float4*>(
                    x_in + (((size_t)(b * H + hh) * W + ww) << 4) + ch);
                const float4 q0 = p4[0], q1 = p4[1];
                const float xv[8] = {q0.x, q0.y, q0.z, q0.w, q1.x, q1.y, q1.z, q1.w};
                const int tap = (di + 1) * 3 + (dj + 1);
                #pragma unroll
                for (int j = 0; j < 8; ++j)
                    z[j] = fmaf(xv[j], pw[tap * 16 + ch + j], z[j]);
                if (di == 0 && dj == 0) {
                    #pragma unroll
                    for (int j = 0; j < 8; ++j) xcen[j] = xv[j];
                }
            }
        }

        const float4 xold4 = *reinterpret_cast<const float4*>(
            x_in + ((size_t)(cellbase + m) << 4) + g * 4);

        // ---- A-frags (K=64: k0-31 = [x | z1], k32-63 = [z2 | prog | pad])
        bf16x8 a0h, a0l, a1h, a1l;
        #pragma unroll
        for (int j = 0; j < 8; ++j) {
            const float f0 = (g < 2) ? xcen[j] : z[j];
            const float f1 = (g < 2) ? z[j] : ((g == 2 && j == 0) ? prog : 0.0f);
            const unsigned short h0 = bf16_hi(f0);
            a0h[j] = (short)h0;  a0l[j] = (short)bf16_hi(f0 - bf16_f32(h0));
            const unsigned short h1 = bf16_hi(f1);
            a1h[j] = (short)h1;  a1l[j] = (short)bf16_hi(f1 - bf16_f32(h1));
        }

        if (t == 0) __syncthreads();   // staged wlds visible (uniform branch)

        // ---- fc0: h[16 cells][128 hid]; D: lane(g,m) reg r -> h[cell g*4+r][hid nt*16+m]
        #pragma unroll
        for (int nt = 0; nt < 8; ++nt) {
            const int rb = nt << 10;
            const bf16x8 b0h = *reinterpret_cast<const bf16x8*>(&wlds[rb + lb]);
            const bf16x8 b0l = *reinterpret_cast<const bf16x8*>(&wlds[rb + 256 + lb]);
            const bf16x8 b1h = *reinterpret_cast<const bf16x8*>(&wlds[rb + 512 + lb]);
            const bf16x8 b1l = *reinterpret_cast<const bf16x8*>(&wlds[rb + 768 + lb]);
            f32x4 acc = {0.0f, 0.0f, 0.0f, 0.0f};
            acc = __builtin_amdgcn_mfma_f32_16x16x32_bf16(a0h, b0h, acc, 0, 0, 0);
            acc = __builtin_amdgcn_mfma_f32_16x16x32_bf16(a0l, b0h, acc, 0, 0, 0);
            acc = __builtin_amdgcn_mfma_f32_16x16x32_bf16(a0h, b0l, acc, 0, 0, 0);
            acc = __builtin_amdgcn_mfma_f32_16x16x32_bf16(a1h, b1h, acc, 0, 0, 0);
            acc = __builtin_amdgcn_mfma_f32_16x16x32_bf16(a1l, b1h, acc, 0, 0, 0);
            acc = __builtin_amdgcn_mfma_f32_16x16x32_bf16(a1h, b1l, acc, 0, 0, 0);
            const int hid4 = (nt << 2) + (m >> 2), ml = m & 3;
            #pragma unroll
            for (int r = 0; r < 4; ++r) {
                const int cr = g * 4 + r;
                hb[cr * 128 + (((hid4 ^ (cr & 7)) << 2) | ml)] = fmaxf(acc[r] + bias[nt], 0.0f);
            }
        }
        // no block barrier: hlds is wave-private; DS ops complete in order per wave

        // ---- fc1 swapped: D2 = W1 . h^T; lane(g,m) reads h[cell m][hid ks*32+g*8..+7]
        f32x4 acc2 = {0.0f, 0.0f, 0.0f, 0.0f};
        #pragma unroll
        for (int ks = 0; ks < 4; ++ks) {
            const float4 h0 = *reinterpret_cast<const float4*>(
                &hb[m * 128 + ((((ks << 3) + (g << 1) + 0) ^ m7) << 2)]);
            const float4 h1 = *reinterpret_cast<const float4*>(
                &hb[m * 128 + ((((ks << 3) + (g << 1) + 1) ^ m7) << 2)]);
            const float hv[8] = {h0.x, h0.y, h0.z, h0.w, h1.x, h1.y, h1.z, h1.w};
            bf16x8 bh, bl;
            #pragma unroll
            for (int j = 0; j < 8; ++j) {
                const unsigned short hi = bf16_hi(hv[j]);
                bh[j] = (short)hi;
                bl[j] = (short)bf16_hi(hv[j] - bf16_f32(hi));
            }
            acc2 = __builtin_amdgcn_mfma_f32_16x16x32_bf16(w1f[ks * 2 + 0], bh, acc2, 0, 0, 0);
            acc2 = __builtin_amdgcn_mfma_f32_16x16x32_bf16(w1f[ks * 2 + 1], bh, acc2, 0, 0, 0);
            acc2 = __builtin_amdgcn_mfma_f32_16x16x32_bf16(w1f[ks * 2 + 0], bl, acc2, 0, 0, 0);
        }

        // ---- epilogue: D2 lane(g,m) reg r -> dx[ch g*4+r][cell cellbase+m]
        const size_t cell = (size_t)(cellbase + m);
        float4 xn;
        xn.x = xold4.x + 1.0f / (1.0f + __expf(-acc2[0]));
        xn.y = xold4.y + 1.0f / (1.0f + __expf(-acc2[1]));
        xn.z = xold4.z + 1.0f / (1.0f + __expf(-acc2[2]));
        xn.w = xold4.w + 1.0f / (1.0f + __expf(-acc2[3]));
        *reinterpret_cast<float4*>(x_out + (cell << 4) + g * 4) = xn;
        if (snapmask) {
            #pragma unroll
            for (int tt = 0; tt < T; ++tt) {
                if (snapmask & (1 << tt)) {
                    *reinterpret_cast<float4*>(out + (size_t)(b * T + tt) * (H * W * C)
                        + (((size_t)hrow * W + wbase + m) << 4) + g * 4) = xn;
                }
            }
        }
    }
}

extern "C" void kernel_launch(void* const* d_in, const int* in_sizes, int n_in,
                              void* d_out, int out_size, void* d_ws, size_t ws_size,
                              hipStream_t stream) {
    const float* inputs = (const float*)d_in[0];
    const int*   acq    = (const int*)d_in[1];
    const float* p0_w   = (const float*)d_in[2];
    const float* p0_b   = (const float*)d_in[3];
    const float* p1_w   = (const float*)d_in[4];
    const float* p1_b   = (const float*)d_in[5];
    const float* fc0_w  = (const float*)d_in[6];
    const float* fc0_b  = (const float*)d_in[7];
    const float* fc1_w  = (const float*)d_in[8];
    float* out = (float*)d_out;

    const size_t state_elems = (size_t)B * H * W * C;   // 16 MB each
    float* bufA = (float*)d_ws;
    float* bufB = bufA + state_elems;
    unsigned short* pack = (unsigned short*)(bufB + state_elems);  // 40 KB

    zero_acq0<<<B * T, 256, 0, stream>>>(acq, out);
    prep_pack<<<1, 256, 0, stream>>>(fc0_w, fc1_w, pack);

    const int n_cells = B * H * W;                 // 262144
    const dim3 grid(n_cells / 256), block(256);    // 1024 blocks, 4 tiles each

    const float* xin = inputs;
    for (int step = 0; step < NSTEPS; ++step) {
        float* xout = (step & 1) ? bufB : bufA;
        nca_step<<<grid, block, 0, stream>>>(
            xin, xout, p0_w, p0_b, p1_w, p1_b,
            pack, fc0_b, acq, out, step);
        xin = xout;
    }
}